// Round 1
// baseline (23299.191 us; speedup 1.0000x reference)
//
#include <hip/hip_runtime.h>
#include <hip/hip_cooperative_groups.h>

namespace cg = cooperative_groups;

#define BATCH 64
#define SEQT  512
#define DIM   1024

// ---------------------------------------------------------------------------
// Transpose U_w (D x D): uwT[k][j] = U_w[j][k]
// ---------------------------------------------------------------------------
__global__ __launch_bounds__(256) void transpose_uw(const float* __restrict__ in,
                                                    float* __restrict__ out) {
    __shared__ float tile[32][33];
    int bx = blockIdx.x & 31, by = blockIdx.x >> 5;
    int tx = threadIdx.x & 31, ty = threadIdx.x >> 5;  // ty = 0..7
#pragma unroll
    for (int i = 0; i < 32; i += 8)
        tile[ty + i][tx] = in[(size_t)(by * 32 + ty + i) * DIM + bx * 32 + tx];
    __syncthreads();
#pragma unroll
    for (int i = 0; i < 32; i += 8)
        out[(size_t)(bx * 32 + ty + i) * DIM + by * 32 + tx] = tile[tx][ty + i];
}

// ---------------------------------------------------------------------------
// Phase 1: wx = x @ W_w^T + W_b   (fp32, 64x64 tile, BK=16, 4x4 micro-tile)
// out layout [B*T][D]; written into d_out's resultEmbs region (overwritten
// in place by the scan later).
// ---------------------------------------------------------------------------
__global__ __launch_bounds__(256) void gemm_wx(const float* __restrict__ x,
                                               const float* __restrict__ Ww,
                                               const float* __restrict__ Wb,
                                               float* __restrict__ out) {
    __shared__ float As[16][64];  // [kk][m] transposed tiles for b128 reads
    __shared__ float Bs[16][64];  // [kk][n]

    const int tid = threadIdx.x;
    const int nb = blockIdx.x & 15;  // 16 n-blocks
    const int mb = blockIdx.x >> 4;  // 512 m-blocks
    const int m0 = mb * 64, n0 = nb * 64;
    const int tx = tid & 15, ty = tid >> 4;
    const int r0 = ty * 4, c0 = tx * 4;

    float acc[4][4] = {};

    const int lrow = tid >> 2;          // 0..63
    const int lk = (tid & 3) * 4;       // 0,4,8,12
    const float* xa = x + (size_t)(m0 + lrow) * DIM + lk;
    const float* wa = Ww + (size_t)(n0 + lrow) * DIM + lk;

    for (int kt = 0; kt < DIM / 16; ++kt) {
        float4 av = *(const float4*)xa;
        float4 bv = *(const float4*)wa;
        __syncthreads();  // previous tile fully consumed
        As[lk + 0][lrow] = av.x; As[lk + 1][lrow] = av.y;
        As[lk + 2][lrow] = av.z; As[lk + 3][lrow] = av.w;
        Bs[lk + 0][lrow] = bv.x; Bs[lk + 1][lrow] = bv.y;
        Bs[lk + 2][lrow] = bv.z; Bs[lk + 3][lrow] = bv.w;
        __syncthreads();
#pragma unroll
        for (int kk = 0; kk < 16; ++kk) {
            float4 a = *(const float4*)&As[kk][r0];
            float4 b = *(const float4*)&Bs[kk][c0];
            acc[0][0] += a.x * b.x; acc[0][1] += a.x * b.y; acc[0][2] += a.x * b.z; acc[0][3] += a.x * b.w;
            acc[1][0] += a.y * b.x; acc[1][1] += a.y * b.y; acc[1][2] += a.y * b.z; acc[1][3] += a.y * b.w;
            acc[2][0] += a.z * b.x; acc[2][1] += a.z * b.y; acc[2][2] += a.z * b.z; acc[2][3] += a.z * b.w;
            acc[3][0] += a.w * b.x; acc[3][1] += a.w * b.y; acc[3][2] += a.w * b.z; acc[3][3] += a.w * b.w;
        }
        xa += 16; wa += 16;
    }

    float4 wb = *(const float4*)(Wb + n0 + c0);
#pragma unroll
    for (int i = 0; i < 4; ++i) {
        float4 o;
        o.x = acc[i][0] + wb.x; o.y = acc[i][1] + wb.y;
        o.z = acc[i][2] + wb.z; o.w = acc[i][3] + wb.w;
        *(float4*)(out + (size_t)(m0 + r0 + i) * DIM + n0 + c0) = o;
    }
}

// ---------------------------------------------------------------------------
// Phase 2: persistent cooperative scan over T steps.
// grid = 256 blocks (64 j-groups x 4 b-groups), 512 threads (8 waves).
// Block tile: 16 j x 16 b. Thread: 4j x 4b micro-tile, k split 32 ways
// (8 waves x 4 in-lane slots, interleaved). h buffers transposed [j][b].
// uwT is U_w transposed: uwT[k][j].
// ---------------------------------------------------------------------------
__global__ __launch_bounds__(512) void rnn_scan(const float* __restrict__ uwT,
                                                const float* __restrict__ Ub,
                                                const float* __restrict__ bias,
                                                float* __restrict__ out,   // [B][T][D] holds wx, overwritten
                                                float* __restrict__ h0,    // [D][64]
                                                float* __restrict__ h1) {  // [D][64]
    cg::grid_group grid = cg::this_grid();
    __shared__ float red_s[8 * 256];
    __shared__ float val_s[256];

    const int tid = threadIdx.x;
    const int lane = tid & 63;
    const int w = tid >> 6;            // wave 0..7
    const int jt = lane & 3;           // 4 j-tiles
    const int bt = (lane >> 2) & 3;    // 4 b-tiles
    const int ks = lane >> 4;          // 0..3 in-wave k split
    const int kslot = w * 4 + ks;      // 0..31; thread's k set = {kslot + 32*i}

    const int jg = blockIdx.x >> 2;    // 0..63
    const int bg = blockIdx.x & 3;     // 0..3
    const int j0 = jg * 16;
    const int b0 = bg * 16;

    float cst = 0.f;
    if (tid < 256) {
        int jl = tid & 15;
        cst = Ub[j0 + jl] + bias[j0 + jl];
    }

    const float* uw_base = uwT + (size_t)kslot * DIM + j0 + jt * 4;
    const size_t h_off = (size_t)kslot * BATCH + b0 + bt * 4;

    for (int t = 0; t < SEQT; ++t) {
        const float* hc = (t & 1) ? h1 : h0;
        float* hn = (t & 1) ? h0 : h1;

        float acc[4][4] = {};  // [jj][bb]
        const float* up = uw_base;
        const float* hp = hc + h_off;
#pragma unroll 4
        for (int i = 0; i < 32; ++i) {
            float4 uv = *(const float4*)up;  // 4 j at this k
            float4 hv = *(const float4*)hp;  // 4 b at this k
            acc[0][0] += uv.x * hv.x; acc[0][1] += uv.x * hv.y; acc[0][2] += uv.x * hv.z; acc[0][3] += uv.x * hv.w;
            acc[1][0] += uv.y * hv.x; acc[1][1] += uv.y * hv.y; acc[1][2] += uv.y * hv.z; acc[1][3] += uv.y * hv.w;
            acc[2][0] += uv.z * hv.x; acc[2][1] += uv.z * hv.y; acc[2][2] += uv.z * hv.z; acc[2][3] += uv.z * hv.w;
            acc[3][0] += uv.w * hv.x; acc[3][1] += uv.w * hv.y; acc[3][2] += uv.w * hv.z; acc[3][3] += uv.w * hv.w;
            up += (size_t)32 * DIM;
            hp += (size_t)32 * BATCH;
        }

        // reduce across the 4 in-wave k slots (lanes ^16, ^32)
#pragma unroll
        for (int jj = 0; jj < 4; ++jj)
#pragma unroll
            for (int bb = 0; bb < 4; ++bb) {
                float v = acc[jj][bb];
                v += __shfl_xor(v, 16, 64);
                v += __shfl_xor(v, 32, 64);
                acc[jj][bb] = v;
            }
        if (ks == 0) {
#pragma unroll
            for (int jj = 0; jj < 4; ++jj)
#pragma unroll
                for (int bb = 0; bb < 4; ++bb)
                    red_s[w * 256 + (bt * 4 + bb) * 16 + jt * 4 + jj] = acc[jj][bb];
        }
        __syncthreads();

        if (tid < 256) {  // pass A: reduce waves, tanh, write out (j-fast, coalesced)
            float s = 0.f;
#pragma unroll
            for (int ww = 0; ww < 8; ++ww) s += red_s[ww * 256 + tid];
            int jl = tid & 15, bl = tid >> 4;
            size_t idx = ((size_t)(b0 + bl) * SEQT + t) * DIM + (j0 + jl);
            float v = tanhf(out[idx] + s + cst);
            out[idx] = v;
            val_s[tid] = v;
            if (t == SEQT - 1)
                out[(size_t)BATCH * SEQT * DIM + (size_t)(b0 + bl) * DIM + (j0 + jl)] = v;
        }
        __syncthreads();
        if (tid < 256) {  // pass B: write transposed h (b-fast, coalesced)
            int bl = tid & 15, jl = tid >> 4;
            hn[(size_t)(j0 + jl) * BATCH + (b0 + bl)] = val_s[bl * 16 + jl];
        }
        grid.sync();
    }
}

// ---------------------------------------------------------------------------
extern "C" void kernel_launch(void* const* d_in, const int* in_sizes, int n_in,
                              void* d_out, int out_size, void* d_ws, size_t ws_size,
                              hipStream_t stream) {
    const float* x    = (const float*)d_in[0];
    const float* W_w  = (const float*)d_in[1];
    const float* W_b  = (const float*)d_in[2];
    const float* U_w  = (const float*)d_in[3];
    const float* U_b  = (const float*)d_in[4];
    const float* bias = (const float*)d_in[5];
    float* out = (float*)d_out;

    // ws layout: [0, 4MB) uwT ; [4MB, +256KB) h0 ; [+256KB, +256KB) h1
    float* uwT = (float*)d_ws;
    float* h0  = uwT + (size_t)DIM * DIM;
    float* h1  = h0 + (size_t)DIM * BATCH;

    // h0/h1 = 0 (harness poisons ws with 0xAA)
    hipMemsetAsync((void*)h0, 0, 2 * (size_t)DIM * BATCH * sizeof(float), stream);

    transpose_uw<<<dim3(1024), dim3(256), 0, stream>>>(U_w, uwT);

    gemm_wx<<<dim3((32768 / 64) * (DIM / 64)), dim3(256), 0, stream>>>(x, W_w, W_b, out);

    void* args[] = {(void*)&uwT, (void*)&U_b, (void*)&bias,
                    (void*)&out, (void*)&h0, (void*)&h1};
    hipLaunchCooperativeKernel((void*)rnn_scan, dim3(256), dim3(512), args, 0, stream);
}

// Round 2
// 11982.623 us; speedup vs baseline: 1.9444x; 1.9444x over previous
//
#include <hip/hip_runtime.h>
#include <hip/hip_cooperative_groups.h>

#define BATCH 64
#define SEQT  512
#define DIM   1024

#define JB   32                 // j-rows per block
#define BB   8                  // batches per block
#define NJG  (DIM / JB)         // 32 j-groups (column size)
#define NBG  (BATCH / BB)       // 8 independent columns
#define NBLK (NJG * NBG)        // 256 blocks
#define NTHR 512
#define UPITCH 36               // padded LDS row (32 + 4), keeps 16B align

// dynamic LDS carve-up (floats)
#define LDS_U    (DIM * UPITCH)          // 147456 B
#define LDS_RED  (8 * 256)               // 8192 B
#define LDS_VAL  (256)                   // 1024 B
#define LDS_BYTES ((LDS_U + LDS_RED + LDS_VAL) * 4)   // 156672 < 163840

// ---------------------------------------------------------------------------
// Phase 1: wx = x @ W_w^T + W_b  (fp32, 64x64 tile, BK=16, 4x4 micro-tile)
// Written into d_out's resultEmbs region; overwritten in place by the scan.
// ---------------------------------------------------------------------------
__global__ __launch_bounds__(256) void gemm_wx(const float* __restrict__ x,
                                               const float* __restrict__ Ww,
                                               const float* __restrict__ Wb,
                                               float* __restrict__ out) {
    __shared__ float As[16][64];
    __shared__ float Bs[16][64];

    const int tid = threadIdx.x;
    const int nb = blockIdx.x & 15;
    const int mb = blockIdx.x >> 4;
    const int m0 = mb * 64, n0 = nb * 64;
    const int tx = tid & 15, ty = tid >> 4;
    const int r0 = ty * 4, c0 = tx * 4;

    float acc[4][4] = {};

    const int lrow = tid >> 2;
    const int lk = (tid & 3) * 4;
    const float* xa = x + (size_t)(m0 + lrow) * DIM + lk;
    const float* wa = Ww + (size_t)(n0 + lrow) * DIM + lk;

    for (int kt = 0; kt < DIM / 16; ++kt) {
        float4 av = *(const float4*)xa;
        float4 bv = *(const float4*)wa;
        __syncthreads();
        As[lk + 0][lrow] = av.x; As[lk + 1][lrow] = av.y;
        As[lk + 2][lrow] = av.z; As[lk + 3][lrow] = av.w;
        Bs[lk + 0][lrow] = bv.x; Bs[lk + 1][lrow] = bv.y;
        Bs[lk + 2][lrow] = bv.z; Bs[lk + 3][lrow] = bv.w;
        __syncthreads();
#pragma unroll
        for (int kk = 0; kk < 16; ++kk) {
            float4 a = *(const float4*)&As[kk][r0];
            float4 b = *(const float4*)&Bs[kk][c0];
            acc[0][0] += a.x * b.x; acc[0][1] += a.x * b.y; acc[0][2] += a.x * b.z; acc[0][3] += a.x * b.w;
            acc[1][0] += a.y * b.x; acc[1][1] += a.y * b.y; acc[1][2] += a.y * b.z; acc[1][3] += a.y * b.w;
            acc[2][0] += a.z * b.x; acc[2][1] += a.z * b.y; acc[2][2] += a.z * b.z; acc[2][3] += a.z * b.w;
            acc[3][0] += a.w * b.x; acc[3][1] += a.w * b.y; acc[3][2] += a.w * b.z; acc[3][3] += a.w * b.w;
        }
        xa += 16; wa += 16;
    }

    float4 wb = *(const float4*)(Wb + n0 + c0);
#pragma unroll
    for (int i = 0; i < 4; ++i) {
        float4 o;
        o.x = acc[i][0] + wb.x; o.y = acc[i][1] + wb.y;
        o.z = acc[i][2] + wb.z; o.w = acc[i][3] + wb.w;
        *(float4*)(out + (size_t)(m0 + r0 + i) * DIM + n0 + c0) = o;
    }
}

// ---------------------------------------------------------------------------
// Phase 2: persistent cooperative scan, U-slice resident in LDS.
// 256 blocks = 32 jg x 8 bg. Block tile 32j x 8b, all k.
// Thread: (ksl[2b lane-low] | jt[3b] | bt[1b] | wave[3b]) ->
//   4j x 4b micro-tile, k split 32 ways (kslot = wave*4+ksl).
// Custom per-column barrier (32 blocks) replaces grid.sync so the L2
// stays warm and only h (+wx stream) crosses the coherence point.
// ---------------------------------------------------------------------------
__global__ __launch_bounds__(NTHR, 1) void rnn_scan2(
    const float* __restrict__ Uw,   // [j][k] original layout
    const float* __restrict__ Ub,
    const float* __restrict__ bias,
    float* __restrict__ out,        // [B][T][D] holds wx, overwritten; +hT tail
    float* __restrict__ h0,         // [D][64]
    float* __restrict__ h1,         // [D][64]
    unsigned* __restrict__ bar) {   // barrier state (zeroed)
    extern __shared__ float lds[];
    float* Ulds = lds;                    // [DIM][UPITCH], Ulds[k][c]=Uw[j0+c][k]
    float* red  = lds + LDS_U;            // [8 waves][256]
    float* val  = red + LDS_RED;          // [256]

    const int tid = threadIdx.x;
    const int bg = blockIdx.x & 7;
    const int jg = blockIdx.x >> 3;
    const int j0 = jg * JB;
    const int b0 = bg * BB;

    // one-time LDS fill of this block's U-slice (transposed to [k][j])
    {
        int c = tid & 31;
        int kc = (tid >> 5) << 6;  // 16 chunks of 64 k
        const float* src = Uw + (size_t)(j0 + c) * DIM + kc;
#pragma unroll
        for (int i = 0; i < 16; ++i) {
            float4 v = *(const float4*)(src + i * 4);
            int k = kc + i * 4;
            Ulds[(k + 0) * UPITCH + c] = v.x;
            Ulds[(k + 1) * UPITCH + c] = v.y;
            Ulds[(k + 2) * UPITCH + c] = v.z;
            Ulds[(k + 3) * UPITCH + c] = v.w;
        }
    }

    float cst = 0.f;
    if (tid < 256) {
        int jl = tid & 31;
        cst = Ub[j0 + jl] + bias[j0 + jl];
    }
    __syncthreads();

    const int ksl = tid & 3;
    const int jt  = (tid >> 2) & 7;
    const int bt  = (tid >> 5) & 1;
    const int w   = tid >> 6;
    const int kslot = (w << 2) | ksl;   // 0..31

    unsigned* cnt = bar + (size_t)bg * 16;        // 64 B apart per column
    unsigned* gen = bar + 512 + (size_t)bg * 16;

    const float* uw_p0 = Ulds + (size_t)kslot * UPITCH + jt * 4;
    const size_t hoff = (size_t)kslot * BATCH + b0 + bt * 4;

    for (int t = 0; t < SEQT; ++t) {
        const float* hc = (t & 1) ? h1 : h0;
        float* hn = (t & 1) ? h0 : h1;

        // prefetch this step's wx early (latency hidden behind k-loop)
        float wxv = 0.f;
        size_t oidx = 0;
        if (tid < 256) {
            int jl = tid & 31, bl = tid >> 5;
            oidx = ((size_t)(b0 + bl) * SEQT + t) * DIM + (j0 + jl);
            wxv = out[oidx];
        }

        float acc[4][4] = {};   // [jj][bb]
        const float* up = uw_p0;
        const float* hp = hc + hoff;
#pragma unroll 8
        for (int i = 0; i < 32; ++i) {
            float4 u = *(const float4*)up;   // 4 j at this k (LDS)
            float4 h = *(const float4*)hp;   // 4 b at this k (global)
            acc[0][0] += u.x * h.x; acc[0][1] += u.x * h.y; acc[0][2] += u.x * h.z; acc[0][3] += u.x * h.w;
            acc[1][0] += u.y * h.x; acc[1][1] += u.y * h.y; acc[1][2] += u.y * h.z; acc[1][3] += u.y * h.w;
            acc[2][0] += u.z * h.x; acc[2][1] += u.z * h.y; acc[2][2] += u.z * h.z; acc[2][3] += u.z * h.w;
            acc[3][0] += u.w * h.x; acc[3][1] += u.w * h.y; acc[3][2] += u.w * h.z; acc[3][3] += u.w * h.w;
            up += 32 * UPITCH;
            hp += 32 * BATCH;
        }

        // reduce the 4 in-wave k-slots (lane bits 0,1)
#pragma unroll
        for (int jj = 0; jj < 4; ++jj)
#pragma unroll
            for (int bb = 0; bb < 4; ++bb) {
                float v = acc[jj][bb];
                v += __shfl_xor(v, 1, 64);
                v += __shfl_xor(v, 2, 64);
                acc[jj][bb] = v;
            }
        if (ksl == 0) {
#pragma unroll
            for (int jj = 0; jj < 4; ++jj)
#pragma unroll
                for (int bb = 0; bb < 4; ++bb)
                    red[w * 256 + (bt * 4 + bb) * 32 + jt * 4 + jj] = acc[jj][bb];
        }
        __syncthreads();

        if (tid < 256) {  // cross-wave reduce + tanh + out write (j-fast)
            float s = 0.f;
#pragma unroll
            for (int ww = 0; ww < 8; ++ww) s += red[ww * 256 + tid];
            float v = tanhf(wxv + s + cst);
            out[oidx] = v;
            val[tid] = v;
            if (t == SEQT - 1)
                out[(size_t)BATCH * SEQT * DIM + (size_t)(b0 + (tid >> 5)) * DIM + (j0 + (tid & 31))] = v;
        }
        __syncthreads();
        if (tid < 256) {  // publish h transposed [j][b] (b-fast)
            int bl = tid & 7, jl = tid >> 3;
            hn[(size_t)(j0 + jl) * BATCH + (b0 + bl)] = val[bl * 32 + jl];
        }

        if (t < SEQT - 1) {
            __syncthreads();  // all hn stores issued block-wide
            if (tid == 0) {
                __builtin_amdgcn_fence(__ATOMIC_RELEASE, "agent");
                unsigned old = __hip_atomic_fetch_add(cnt, 1u, __ATOMIC_ACQ_REL,
                                                      __HIP_MEMORY_SCOPE_AGENT);
                unsigned want = (unsigned)(NJG * (t + 1));
                if (old == want - 1) {
                    __hip_atomic_store(gen, (unsigned)(t + 1), __ATOMIC_RELEASE,
                                       __HIP_MEMORY_SCOPE_AGENT);
                } else {
                    while (__hip_atomic_load(gen, __ATOMIC_RELAXED,
                                             __HIP_MEMORY_SCOPE_AGENT) < (unsigned)(t + 1)) {
                        __builtin_amdgcn_s_sleep(2);
                    }
                }
                __builtin_amdgcn_fence(__ATOMIC_ACQUIRE, "agent");
            }
            __syncthreads();
        }
    }
}

// ---------------------------------------------------------------------------
extern "C" void kernel_launch(void* const* d_in, const int* in_sizes, int n_in,
                              void* d_out, int out_size, void* d_ws, size_t ws_size,
                              hipStream_t stream) {
    const float* x    = (const float*)d_in[0];
    const float* W_w  = (const float*)d_in[1];
    const float* W_b  = (const float*)d_in[2];
    const float* U_w  = (const float*)d_in[3];
    const float* U_b  = (const float*)d_in[4];
    const float* bias = (const float*)d_in[5];
    float* out = (float*)d_out;

    // ws: [0,4K) barrier state ; [4K, +256K) h0 ; then h1
    unsigned* bar = (unsigned*)d_ws;
    float* h0 = (float*)((char*)d_ws + 4096);
    float* h1 = h0 + (size_t)DIM * BATCH;

    hipMemsetAsync(d_ws, 0, 4096 + 2 * (size_t)DIM * BATCH * sizeof(float), stream);

    gemm_wx<<<dim3((32768 / 64) * (DIM / 64)), dim3(256), 0, stream>>>(x, W_w, W_b, out);

    static bool attr_done = false;
    if (!attr_done) {
        hipFuncSetAttribute((const void*)rnn_scan2,
                            hipFuncAttributeMaxDynamicSharedMemorySize, LDS_BYTES);
        attr_done = true;
    }

    void* args[] = {(void*)&U_w, (void*)&U_b, (void*)&bias,
                    (void*)&out, (void*)&h0, (void*)&h1, (void*)&bar};
    hipLaunchCooperativeKernel((void*)rnn_scan2, dim3(NBLK), dim3(NTHR), args,
                               LDS_BYTES, stream);
}

// Round 4
// 9360.515 us; speedup vs baseline: 2.4891x; 1.2801x over previous
//
#include <hip/hip_runtime.h>

#define BATCH 64
#define SEQT  512
#define DIM   1024

#define JB   32                 // j-rows per block
#define BB   8                  // batches per block
#define NJG  (DIM / JB)         // 32 j-groups (column size)
#define NBG  (BATCH / BB)       // 8 independent columns
#define NBLK (NJG * NBG)        // 256 blocks
#define NTHR 512
#define UPITCH 34               // 8B-aligned rows, (2k+c)%32 banks -> ~2-way (free)

// dynamic LDS carve-up (floats)
#define LDS_U    (DIM * UPITCH)          // 139264 B
#define LDS_RED  (8 * 256)               // 8192 B
#define LDS_VAL  (256)                   // 1024 B
#define LDS_BYTES ((LDS_U + LDS_RED + LDS_VAL) * 4)   // 148480 < 163840

typedef unsigned long long ull;

union F2U {
    ull u;
    float f[2];
};

// ---------------------------------------------------------------------------
// Phase 1: wx = x @ W_w^T + W_b  (fp32, 64x64 tile, BK=16, 4x4 micro-tile)
// ---------------------------------------------------------------------------
__global__ __launch_bounds__(256) void gemm_wx(const float* __restrict__ x,
                                               const float* __restrict__ Ww,
                                               const float* __restrict__ Wb,
                                               float* __restrict__ out) {
    __shared__ float As[16][64];
    __shared__ float Bs[16][64];

    const int tid = threadIdx.x;
    const int nb = blockIdx.x & 15;
    const int mb = blockIdx.x >> 4;
    const int m0 = mb * 64, n0 = nb * 64;
    const int tx = tid & 15, ty = tid >> 4;
    const int r0 = ty * 4, c0 = tx * 4;

    float acc[4][4] = {};

    const int lrow = tid >> 2;
    const int lk = (tid & 3) * 4;
    const float* xa = x + (size_t)(m0 + lrow) * DIM + lk;
    const float* wa = Ww + (size_t)(n0 + lrow) * DIM + lk;

    for (int kt = 0; kt < DIM / 16; ++kt) {
        float4 av = *(const float4*)xa;
        float4 bv = *(const float4*)wa;
        __syncthreads();
        As[lk + 0][lrow] = av.x; As[lk + 1][lrow] = av.y;
        As[lk + 2][lrow] = av.z; As[lk + 3][lrow] = av.w;
        Bs[lk + 0][lrow] = bv.x; Bs[lk + 1][lrow] = bv.y;
        Bs[lk + 2][lrow] = bv.z; Bs[lk + 3][lrow] = bv.w;
        __syncthreads();
#pragma unroll
        for (int kk = 0; kk < 16; ++kk) {
            float4 a = *(const float4*)&As[kk][r0];
            float4 b = *(const float4*)&Bs[kk][c0];
            acc[0][0] += a.x * b.x; acc[0][1] += a.x * b.y; acc[0][2] += a.x * b.z; acc[0][3] += a.x * b.w;
            acc[1][0] += a.y * b.x; acc[1][1] += a.y * b.y; acc[1][2] += a.y * b.z; acc[1][3] += a.y * b.w;
            acc[2][0] += a.z * b.x; acc[2][1] += a.z * b.y; acc[2][2] += a.z * b.z; acc[2][3] += a.z * b.w;
            acc[3][0] += a.w * b.x; acc[3][1] += a.w * b.y; acc[3][2] += a.w * b.z; acc[3][3] += a.w * b.w;
        }
        xa += 16; wa += 16;
    }

    float4 wb = *(const float4*)(Wb + n0 + c0);
#pragma unroll
    for (int i = 0; i < 4; ++i) {
        float4 o;
        o.x = acc[i][0] + wb.x; o.y = acc[i][1] + wb.y;
        o.z = acc[i][2] + wb.z; o.w = acc[i][3] + wb.w;
        *(float4*)(out + (size_t)(m0 + r0 + i) * DIM + n0 + c0) = o;
    }
}

// ---------------------------------------------------------------------------
// Phase 2: persistent cooperative scan, U-slice resident in LDS.
// Round 4:
//  - h loads BATCHED into registers (4 double-buffered chunks of 16x8B atomic
//    loads) so coherent-point latency is pipelined, not serialized per use.
//  - h published via RETURNING atomic exchanges: vmcnt retires only on MALL
//    response, so waitcnt-then-flag is a real visibility guarantee (fixes the
//    round-3 replay race without wbl2/inv sweeps).
//  - per-producer flag array + 32-lane ballot poll (no serialized fetch_add).
// ---------------------------------------------------------------------------
__global__ __launch_bounds__(NTHR, 1) void rnn_scan3(
    const float* __restrict__ Uw,   // [j][k] original layout
    const float* __restrict__ Ub,
    const float* __restrict__ bias,
    float* __restrict__ out,        // [B][T][D] holds wx, overwritten; +hT tail
    float* __restrict__ h0,         // [D][64]
    float* __restrict__ h1,         // [D][64]
    unsigned* __restrict__ bar) {   // flags: [bg][jg] spaced 64B, zeroed
    extern __shared__ float lds[];
    float* Ulds = lds;                    // [DIM][UPITCH], Ulds[k][c]=Uw[j0+c][k]
    float* red  = lds + LDS_U;            // [8 waves][256]
    float* val  = red + LDS_RED;          // [256]

    const int tid = threadIdx.x;
    const int bg = blockIdx.x & 7;
    const int jg = blockIdx.x >> 3;
    const int j0 = jg * JB;
    const int b0 = bg * BB;

    // one-time LDS fill of this block's U-slice (transposed to [k][j])
    {
        int c = tid & 31;
        int kc = (tid >> 5) << 6;  // 16 chunks of 64 k
        const float* src = Uw + (size_t)(j0 + c) * DIM + kc;
#pragma unroll
        for (int i = 0; i < 16; ++i) {
            float4 v = *(const float4*)(src + i * 4);
            int k = kc + i * 4;
            Ulds[(k + 0) * UPITCH + c] = v.x;
            Ulds[(k + 1) * UPITCH + c] = v.y;
            Ulds[(k + 2) * UPITCH + c] = v.z;
            Ulds[(k + 3) * UPITCH + c] = v.w;
        }
    }

    float cst = 0.f;
    if (tid < 256) {
        int jl = tid & 31;
        cst = Ub[j0 + jl] + bias[j0 + jl];
    }
    __syncthreads();

    const int ksl = tid & 3;
    const int jt  = (tid >> 2) & 7;
    const int bt  = (tid >> 5) & 1;
    const int w   = tid >> 6;
    const int kslot = (w << 2) | ksl;   // 0..31

    unsigned* myflag = bar + (size_t)bg * 512 + (size_t)jg * 16;

    const float* uw_p0 = Ulds + (size_t)kslot * UPITCH + jt * 4;
    const size_t hoff = (size_t)kslot * BATCH + b0 + bt * 4;  // 8B-aligned pairs

    ull junk = 0;

    for (int t = 0; t < SEQT; ++t) {
        const float* hc = (t & 1) ? h1 : h0;
        float* hn = (t & 1) ? h0 : h1;

        // prefetch this step's wx early (latency hidden behind k-loop)
        float wxv = 0.f;
        size_t oidx = 0;
        if (tid < 256) {
            int jl = tid & 31, bl = tid >> 5;
            oidx = ((size_t)(b0 + bl) * SEQT + t) * DIM + (j0 + jl);
            wxv = out[oidx];
        }

        const ull* hp = (const ull*)hc + hoff / 2;  // step per i: 1024 ull
        F2U bufA[16], bufB[16];

        // prologue: chunk 0 (iterations 0..7), 16 loads back-to-back
#pragma unroll
        for (int j = 0; j < 8; ++j) {
            bufA[2 * j + 0].u = __hip_atomic_load(hp + (size_t)j * 1024 + 0,
                                                  __ATOMIC_RELAXED, __HIP_MEMORY_SCOPE_AGENT);
            bufA[2 * j + 1].u = __hip_atomic_load(hp + (size_t)j * 1024 + 1,
                                                  __ATOMIC_RELAXED, __HIP_MEMORY_SCOPE_AGENT);
        }

        float acc[4][4] = {};   // [jj][bb]
        const float* up = uw_p0;

#pragma unroll
        for (int c = 0; c < 4; ++c) {
            F2U* cur = (c & 1) ? bufB : bufA;
            F2U* nxt = (c & 1) ? bufA : bufB;
            if (c < 3) {
                const ull* hpn = hp + (size_t)(c + 1) * 8 * 1024;
#pragma unroll
                for (int j = 0; j < 8; ++j) {
                    nxt[2 * j + 0].u = __hip_atomic_load(hpn + (size_t)j * 1024 + 0,
                                                         __ATOMIC_RELAXED, __HIP_MEMORY_SCOPE_AGENT);
                    nxt[2 * j + 1].u = __hip_atomic_load(hpn + (size_t)j * 1024 + 1,
                                                         __ATOMIC_RELAXED, __HIP_MEMORY_SCOPE_AGENT);
                }
            }
#pragma unroll
            for (int j = 0; j < 8; ++j) {
                float2 ua = *(const float2*)up;
                float2 ub = *(const float2*)(up + 2);
                float hx = cur[2 * j].f[0], hy = cur[2 * j].f[1];
                float hz = cur[2 * j + 1].f[0], hw = cur[2 * j + 1].f[1];
                acc[0][0] += ua.x * hx; acc[0][1] += ua.x * hy; acc[0][2] += ua.x * hz; acc[0][3] += ua.x * hw;
                acc[1][0] += ua.y * hx; acc[1][1] += ua.y * hy; acc[1][2] += ua.y * hz; acc[1][3] += ua.y * hw;
                acc[2][0] += ub.x * hx; acc[2][1] += ub.x * hy; acc[2][2] += ub.x * hz; acc[2][3] += ub.x * hw;
                acc[3][0] += ub.y * hx; acc[3][1] += ub.y * hy; acc[3][2] += ub.y * hz; acc[3][3] += ub.y * hw;
                up += 32 * UPITCH;
            }
        }

        // reduce the 4 in-wave k-slots (lane bits 0,1)
#pragma unroll
        for (int jj = 0; jj < 4; ++jj)
#pragma unroll
            for (int bb = 0; bb < 4; ++bb) {
                float v = acc[jj][bb];
                v += __shfl_xor(v, 1, 64);
                v += __shfl_xor(v, 2, 64);
                acc[jj][bb] = v;
            }
        if (ksl == 0) {
#pragma unroll
            for (int jj = 0; jj < 4; ++jj)
#pragma unroll
                for (int bb = 0; bb < 4; ++bb)
                    red[w * 256 + (bt * 4 + bb) * 32 + jt * 4 + jj] = acc[jj][bb];
        }
        __syncthreads();

        if (tid < 256) {  // cross-wave reduce + tanh + out write (j-fast)
            float s = 0.f;
#pragma unroll
            for (int ww = 0; ww < 8; ++ww) s += red[ww * 256 + tid];
            float v = tanhf(wxv + s + cst);
            out[oidx] = v;
            val[tid] = v;
            if (t == SEQT - 1)
                out[(size_t)BATCH * SEQT * DIM + (size_t)(b0 + (tid >> 5)) * DIM + (j0 + (tid & 31))] = v;
        }
        __syncthreads();

        if (tid < 128) {  // publish h [j][b] as returning 8B exchanges
            int jl = tid >> 2, m = tid & 3;
            F2U p;
            p.f[0] = val[(2 * m + 0) * 32 + jl];
            p.f[1] = val[(2 * m + 1) * 32 + jl];
            ull old = __hip_atomic_exchange(
                (ull*)(hn + (size_t)(j0 + jl) * BATCH + b0 + 2 * m),
                p.u, __ATOMIC_RELAXED, __HIP_MEMORY_SCOPE_AGENT);
            junk ^= old;  // force returning form; consumed after the loop
        }

        if (t < SEQT - 1) {
            __builtin_amdgcn_s_waitcnt(0);  // exchanges acked AT the coherent point
            __syncthreads();                // whole block's publishes visible
            if (tid == 0)
                __hip_atomic_store(myflag, (unsigned)(t + 1),
                                   __ATOMIC_RELAXED, __HIP_MEMORY_SCOPE_AGENT);
            if (tid < 64) {                 // wave 0 polls all 32 producer flags
                unsigned want = (unsigned)(t + 1);
                unsigned* fp = bar + (size_t)bg * 512 + (size_t)(tid & 31) * 16;
                unsigned f;
                do {
                    f = __hip_atomic_load(fp, __ATOMIC_RELAXED, __HIP_MEMORY_SCOPE_AGENT);
                } while (__ballot(f < want));
            }
            __syncthreads();
        }
    }

    // impossible (NaN-pair pattern tanh can never produce) — keeps the
    // exchange returns live so vmcnt acks are real coherent-point acks.
    if (junk == 0xFFF00001FFF00002ULL) out[0] = -1.0f;
}

// ---------------------------------------------------------------------------
extern "C" void kernel_launch(void* const* d_in, const int* in_sizes, int n_in,
                              void* d_out, int out_size, void* d_ws, size_t ws_size,
                              hipStream_t stream) {
    const float* x    = (const float*)d_in[0];
    const float* W_w  = (const float*)d_in[1];
    const float* W_b  = (const float*)d_in[2];
    const float* U_w  = (const float*)d_in[3];
    const float* U_b  = (const float*)d_in[4];
    const float* bias = (const float*)d_in[5];
    float* out = (float*)d_out;

    // ws: [0,64K) flags ; [64K, +256K) h0 ; then h1
    unsigned* bar = (unsigned*)d_ws;
    float* h0 = (float*)((char*)d_ws + 65536);
    float* h1 = h0 + (size_t)DIM * BATCH;

    hipMemsetAsync(d_ws, 0, 65536 + 2 * (size_t)DIM * BATCH * sizeof(float), stream);

    gemm_wx<<<dim3((32768 / 64) * (DIM / 64)), dim3(256), 0, stream>>>(x, W_w, W_b, out);

    static bool attr_done = false;
    if (!attr_done) {
        hipFuncSetAttribute((const void*)rnn_scan3,
                            hipFuncAttributeMaxDynamicSharedMemorySize, LDS_BYTES);
        attr_done = true;
    }

    void* args[] = {(void*)&U_w, (void*)&U_b, (void*)&bias,
                    (void*)&out, (void*)&h0, (void*)&h1, (void*)&bar};
    hipLaunchCooperativeKernel((void*)rnn_scan3, dim3(NBLK), dim3(NTHR), args,
                               LDS_BYTES, stream);
}